// Round 10
// baseline (153.423 us; speedup 1.0000x reference)
//
#include <hip/hip_runtime.h>

#define NEG_SLOPE 0.2f

typedef unsigned int uint32;
typedef unsigned short ushort;
typedef unsigned long long u64;
typedef __fp16 f16x2 __attribute__((ext_vector_type(2)));
typedef __fp16 half8 __attribute__((ext_vector_type(8)));
typedef float f32x4 __attribute__((ext_vector_type(4)));

constexpr int IN_CH = 128;
constexpr int HID = 32;
constexpr int HEADS = 4;
constexpr int OUT_CH = 64;
constexpr int C1 = HEADS * HID; // 128
constexpr int RB = 1024;        // elements per radix block

__device__ inline uint32 pk_f16(float lo, float hi) {
    f16x2 h = __builtin_amdgcn_cvt_pkrtz(lo, hi);
    uint32 r;
    __builtin_memcpy(&r, &h, 4);
    return r;
}
__device__ inline float f16_lo(uint32 v) {
    f16x2 h;
    __builtin_memcpy(&h, &v, 4);
    return (float)h[0];
}
__device__ inline float f16_hi(uint32 v) {
    f16x2 h;
    __builtin_memcpy(&h, &v, 4);
    return (float)h[1];
}
__device__ inline float leaky(float e) {
    return fmaxf(e, 0.f) + NEG_SLOPE * fminf(e, 0.f);
}

// ========== CSR: MSD-byte (dst>>8) scatter w/ atomic range reservation + LDS local sort ==========
// within-dst edge order is arbitrary (only permutes fp summation; tolerance covers it)

__global__ __launch_bounds__(256) void pack_hist_kernel(const int* __restrict__ ei, int E,
                                                        uint32* __restrict__ packed,
                                                        int* __restrict__ gcount) {
    __shared__ int lh[256];
    int t = threadIdx.x;
    lh[t] = 0;
    __syncthreads();
    int base0 = blockIdx.x * RB;
#pragma unroll
    for (int j = 0; j < 4; j++) {
        int e = base0 + j * 256 + t;
        if (e < E) {
            uint32 s = (uint32)ei[e], d = (uint32)ei[E + e];
            uint32 v = (d << 16) | s;
            packed[e] = v;
            atomicAdd(&lh[v >> 24], 1);
        }
    }
    __syncthreads();
    if (lh[t]) atomicAdd(&gcount[t], lh[t]);
}

__global__ __launch_bounds__(256) void bases_kernel(const int* __restrict__ gcount,
                                                    int* __restrict__ gbase,
                                                    int* __restrict__ cursor, int E) {
    __shared__ int cum[256];
    int t = threadIdx.x;
    int v = gcount[t];
    cum[t] = v;
    __syncthreads();
    for (int d = 1; d < 256; d <<= 1) {
        int x = (t >= d) ? cum[t - d] : 0;
        __syncthreads();
        cum[t] += x;
        __syncthreads();
    }
    int excl = cum[t] - v;
    gbase[t] = excl;
    cursor[t] = excl;
    if (t == 255) gbase[256] = E;
}

__global__ __launch_bounds__(256) void scatter_msd_kernel(const uint32* __restrict__ in,
                                                          uint32* __restrict__ out,
                                                          int* __restrict__ cursor, int E) {
    __shared__ int lcnt[256];
    __shared__ int lbase[256];
    int t = threadIdx.x;
    lcnt[t] = 0;
    __syncthreads();
    int base0 = blockIdx.x * RB;
    uint32 vals[4];
    int bks[4], rank[4];
    bool val[4];
#pragma unroll
    for (int j = 0; j < 4; j++) {
        int e = base0 + j * 256 + t;
        val[j] = e < E;
        uint32 v = val[j] ? in[e] : 0u;
        vals[j] = v;
        int b = v >> 24;
        bks[j] = b;
        if (val[j]) rank[j] = atomicAdd(&lcnt[b], 1);
    }
    __syncthreads();
    if (lcnt[t] > 0) lbase[t] = atomicAdd(&cursor[t], lcnt[t]);
    __syncthreads();
#pragma unroll
    for (int j = 0; j < 4; j++)
        if (val[j]) out[lbase[bks[j]] + rank[j]] = vals[j];
}

// one block per 256-dst bucket: counting sort by (dst & 0xff) + emit offsets[]
__global__ __launch_bounds__(256) void local_sort_kernel(const uint32* __restrict__ in,
                                                         uint32* __restrict__ out,
                                                         const int* __restrict__ gbase,
                                                         int* __restrict__ offsets, int N, int E) {
    __shared__ int hist[256];
    __shared__ int cum[256];
    int b = blockIdx.x;
    int t = threadIdx.x;
    int segstart = gbase[b];
    int segend = gbase[b + 1];
    hist[t] = 0;
    __syncthreads();
    for (int i = segstart + t; i < segend; i += 256) atomicAdd(&hist[(in[i] >> 16) & 0xff], 1);
    __syncthreads();
    int v = hist[t];
    cum[t] = v;
    __syncthreads();
    for (int d = 1; d < 256; d <<= 1) {
        int x = (t >= d) ? cum[t - d] : 0;
        __syncthreads();
        cum[t] += x;
        __syncthreads();
    }
    int myExcl = cum[t] - v;
    int dstv = b * 256 + t;
    if (dstv < N) offsets[dstv] = segstart + myExcl;
    if (b == 0 && t == 0) offsets[N] = E;
    hist[t] = myExcl;
    __syncthreads();
    for (int i = segstart + t; i < segend; i += 256) {
        uint32 w = in[i];
        int slot = atomicAdd(&hist[(w >> 16) & 0xff], 1);
        out[segstart + slot] = w;
    }
}

// ---------------- MFMA f16 GEMM + attention dots + f16 pack ----------------
// BM=64 rows/block, whole K=128 staged once. 4 waves, wave w -> rows w*16..+15.
// A frag: lane l holds A[l&15][(l>>4)*8+j]; B frag: B[(l>>4)*8+j][l&15] via wt[col][k].
// D: col=lane&15, row=(lane>>4)*4+reg (m89-verified mapping).

template <int K, int COLS, int H, bool AF16>
__global__ __launch_bounds__(256) void gemm_dots_kernel(
    const float* __restrict__ A, const float* __restrict__ W,
    const float* __restrict__ att_s, const float* __restrict__ att_d,
    uint32* __restrict__ hb, float* __restrict__ as_, float* __restrict__ ad_, int N) {
    static_assert(K == 128, "");
    constexpr int CF = COLS / 16;
    __shared__ ushort xs[64][136];
    __shared__ ushort wt[COLS][136];
    int tid = threadIdx.x;
    int row0 = blockIdx.x * 64;

#pragma unroll
    for (int l = 0; l < 4; l++) {
        int idx = tid + l * 256;
        int row = idx >> 4, kc = idx & 15;
        uint4 pkv = make_uint4(0, 0, 0, 0);
        if (row0 + row < N) {
            if constexpr (AF16) {
                pkv = *(const uint4*)((const uint32*)A + (size_t)(row0 + row) * (K / 2) + kc * 4);
            } else {
                const float* ap = A + (size_t)(row0 + row) * K + kc * 8;
                float4 v0 = *(const float4*)ap;
                float4 v1 = *(const float4*)(ap + 4);
                pkv = make_uint4(pk_f16(v0.x, v0.y), pk_f16(v0.z, v0.w), pk_f16(v1.x, v1.y),
                                 pk_f16(v1.z, v1.w));
            }
        }
        *(uint4*)&xs[row][kc * 8] = pkv;
    }
    constexpr int NP = (K / 2) * COLS / 256;
#pragma unroll
    for (int l = 0; l < NP; l++) {
        int p = tid + l * 256;
        int col = p % COLS, kp = p / COLS;
        float v0 = W[(size_t)(2 * kp) * COLS + col];
        float v1 = W[(size_t)(2 * kp + 1) * COLS + col];
        *(uint32*)&wt[col][kp * 2] = pk_f16(v0, v1);
    }
    __syncthreads();

    int w = tid >> 6, l = tid & 63;
    int q = l & 15, g = l >> 4;

    half8 af[4];
#pragma unroll
    for (int ks = 0; ks < 4; ks++) af[ks] = *(const half8*)&xs[w * 16 + q][ks * 32 + g * 8];

    f32x4 accs[CF];
#pragma unroll
    for (int cf = 0; cf < CF; cf++) {
        f32x4 a = {0.f, 0.f, 0.f, 0.f};
#pragma unroll
        for (int ks = 0; ks < 4; ks++) {
            half8 bf = *(const half8*)&wt[cf * 16 + q][ks * 32 + g * 8];
            a = __builtin_amdgcn_mfma_f32_16x16x32_f16(af[ks], bf, a, 0, 0, 0);
        }
        accs[cf] = a;
    }

    float asf[CF], adf[CF];
#pragma unroll
    for (int cf = 0; cf < CF; cf++) {
        asf[cf] = att_s[cf * 16 + q];
        adf[cf] = att_d[cf * 16 + q];
    }

#pragma unroll
    for (int r = 0; r < 4; r++) {
        int n_r = row0 + w * 16 + g * 4 + r;
        uint32 dw[CF];
        float p0 = 0.f, p1 = 0.f, p2 = 0.f, p3 = 0.f;
        float d0 = 0.f, d1 = 0.f, d2 = 0.f, d3 = 0.f;
#pragma unroll
        for (int cf = 0; cf < CF; cf++) {
            float v = accs[cf][r];
            float nb = __shfl_xor(v, 1);
            float ev = (q & 1) ? nb : v;
            float ov = (q & 1) ? v : nb;
            dw[cf] = pk_f16(ev, ov);
            float cs = v * asf[cf], cd = v * adf[cf];
            if constexpr (H == 4) {
                if (cf < 2) {
                    p0 += cs;
                    d0 += cd;
                } else if (cf < 4) {
                    p1 += cs;
                    d1 += cd;
                } else if (cf < 6) {
                    p2 += cs;
                    d2 += cd;
                } else {
                    p3 += cs;
                    d3 += cd;
                }
            } else {
                p0 += cs;
                d0 += cd;
            }
        }
#pragma unroll
        for (int dd = 1; dd < 16; dd <<= 1) {
            p0 += __shfl_xor(p0, dd);
            d0 += __shfl_xor(d0, dd);
            if constexpr (H == 4) {
                p1 += __shfl_xor(p1, dd);
                d1 += __shfl_xor(d1, dd);
                p2 += __shfl_xor(p2, dd);
                d2 += __shfl_xor(d2, dd);
                p3 += __shfl_xor(p3, dd);
                d3 += __shfl_xor(d3, dd);
            }
        }
        if (n_r < N) {
            if ((q & 1) == 0) {
                uint32* hp = hb + (size_t)n_r * (COLS / 2) + (q >> 1);
#pragma unroll
                for (int cf = 0; cf < CF; cf++) hp[cf * 8] = dw[cf];
            }
            if constexpr (H == 4) {
                if ((q >> 2) == r) {
                    int hh = q & 3;
                    float vs = hh == 0 ? p0 : hh == 1 ? p1 : hh == 2 ? p2 : p3;
                    float vd = hh == 0 ? d0 : hh == 1 ? d1 : hh == 2 ? d2 : d3;
                    as_[(size_t)n_r * 4 + hh] = vs;
                    ad_[(size_t)n_r * 4 + hh] = vd;
                }
            } else {
                if (q == r) {
                    as_[n_r] = p0;
                    ad_[n_r] = d0;
                }
            }
        }
    }
}

// ---------------- fused single-pass segment softmax + aggregation ----------------

template <int C, int H, bool RELU, bool OUTF16>
__global__ __launch_bounds__(256) void aggregate_kernel(
    const uint32* __restrict__ hb, const float* __restrict__ as_,
    const float* __restrict__ ad_, const int* __restrict__ offsets,
    const uint32* __restrict__ csr, const float* __restrict__ bias, void* __restrict__ outp,
    int N) {
    __shared__ float plds[4][64 * H];
    __shared__ int slds[4][64];
    int gid = blockIdx.x * blockDim.x + threadIdx.x;
    int n = gid >> 6;
    int lane = threadIdx.x & 63;
    int wslot = threadIdx.x >> 6;
    if (n >= N) return;
    int off = offsets[n];
    int deg = offsets[n + 1] - off;

    float ad[H], s[H];
#pragma unroll
    for (int h = 0; h < H; h++) {
        ad[h] = ad_[(size_t)n * H + h];
        s[h] = 0.f;
    }

    constexpr int G = C / 8;
    constexpr int EPI = 64 / G;
    int eg = lane / G;
    int cl = lane % G;
    int hsel = (H == 4) ? (cl >> 2) : 0;
    float acc[8];
#pragma unroll
    for (int j = 0; j < 8; j++) acc[j] = 0.f;

    for (int base = 0; base <= deg; base += 64) {
        int my = base + lane;
        int cnt = min(64, deg + 1 - base);
        if (my <= deg) {
            int si = (my < deg) ? (int)(csr[off + my] & 0xffffu) : n;
            slds[wslot][lane] = si;
            if constexpr (H == 4) {
                float4 a = ((const float4*)as_)[si];
                float q0 = __expf(fminf(leaky(a.x + ad[0]), 80.f));
                float q1 = __expf(fminf(leaky(a.y + ad[1]), 80.f));
                float q2 = __expf(fminf(leaky(a.z + ad[2]), 80.f));
                float q3 = __expf(fminf(leaky(a.w + ad[3]), 80.f));
                s[0] += q0;
                s[1] += q1;
                s[2] += q2;
                s[3] += q3;
                ((float4*)plds[wslot])[lane] = make_float4(q0, q1, q2, q3);
            } else {
                float p = __expf(fminf(leaky(as_[si] + ad[0]), 80.f));
                s[0] += p;
                plds[wslot][lane] = p;
            }
        }
        int t2 = 0;
        for (; t2 + 2 * EPI <= cnt; t2 += 2 * EPI) {
            int tA = t2 + eg, tB = t2 + EPI + eg;
            int srcA = slds[wslot][tA];
            int srcB = slds[wslot][tB];
            float alA = plds[wslot][tA * H + hsel];
            float alB = plds[wslot][tB * H + hsel];
            uint4 uA = *(const uint4*)(hb + (size_t)srcA * (C / 2) + cl * 4);
            uint4 uB = *(const uint4*)(hb + (size_t)srcB * (C / 2) + cl * 4);
            acc[0] = fmaf(alA, f16_lo(uA.x), acc[0]);
            acc[1] = fmaf(alA, f16_hi(uA.x), acc[1]);
            acc[2] = fmaf(alA, f16_lo(uA.y), acc[2]);
            acc[3] = fmaf(alA, f16_hi(uA.y), acc[3]);
            acc[4] = fmaf(alA, f16_lo(uA.z), acc[4]);
            acc[5] = fmaf(alA, f16_hi(uA.z), acc[5]);
            acc[6] = fmaf(alA, f16_lo(uA.w), acc[6]);
            acc[7] = fmaf(alA, f16_hi(uA.w), acc[7]);
            acc[0] = fmaf(alB, f16_lo(uB.x), acc[0]);
            acc[1] = fmaf(alB, f16_hi(uB.x), acc[1]);
            acc[2] = fmaf(alB, f16_lo(uB.y), acc[2]);
            acc[3] = fmaf(alB, f16_hi(uB.y), acc[3]);
            acc[4] = fmaf(alB, f16_lo(uB.z), acc[4]);
            acc[5] = fmaf(alB, f16_hi(uB.z), acc[5]);
            acc[6] = fmaf(alB, f16_lo(uB.w), acc[6]);
            acc[7] = fmaf(alB, f16_hi(uB.w), acc[7]);
        }
        for (; t2 < cnt; t2 += EPI) {
            int te = t2 + eg;
            bool valid = te < cnt;
            int tc = valid ? te : 0;
            int src = slds[wslot][tc];
            float al = plds[wslot][tc * H + hsel];
            al = valid ? al : 0.f;
            uint4 u = *(const uint4*)(hb + (size_t)src * (C / 2) + cl * 4);
            acc[0] = fmaf(al, f16_lo(u.x), acc[0]);
            acc[1] = fmaf(al, f16_hi(u.x), acc[1]);
            acc[2] = fmaf(al, f16_lo(u.y), acc[2]);
            acc[3] = fmaf(al, f16_hi(u.y), acc[3]);
            acc[4] = fmaf(al, f16_lo(u.z), acc[4]);
            acc[5] = fmaf(al, f16_hi(u.z), acc[5]);
            acc[6] = fmaf(al, f16_lo(u.w), acc[6]);
            acc[7] = fmaf(al, f16_hi(u.w), acc[7]);
        }
    }

#pragma unroll
    for (int d = 1; d < 64; d <<= 1)
#pragma unroll
        for (int h = 0; h < H; h++) s[h] += __shfl_xor(s[h], d);
#pragma unroll
    for (int d = G; d < 64; d <<= 1)
#pragma unroll
        for (int j = 0; j < 8; j++) acc[j] += __shfl_xor(acc[j], d);

    if (eg == 0) {
        float inv = 1.f / s[hsel];
        int c = cl * 8;
        float o[8];
#pragma unroll
        for (int j = 0; j < 8; j++) {
            o[j] = fmaf(acc[j], inv, bias[c + j]);
            if (RELU) o[j] = fmaxf(o[j], 0.f);
        }
        if constexpr (OUTF16) {
            uint4 pkv = make_uint4(pk_f16(o[0], o[1]), pk_f16(o[2], o[3]), pk_f16(o[4], o[5]),
                                   pk_f16(o[6], o[7]));
            *(uint4*)((uint32*)outp + (size_t)n * (C / 2) + cl * 4) = pkv;
        } else {
            float* out = (float*)outp;
            *(float4*)(out + (size_t)n * C + c) = make_float4(o[0], o[1], o[2], o[3]);
            *(float4*)(out + (size_t)n * C + c + 4) = make_float4(o[4], o[5], o[6], o[7]);
        }
    }
}

// ---------------- launch ----------------

extern "C" void kernel_launch(void* const* d_in, const int* in_sizes, int n_in,
                              void* d_out, int out_size, void* d_ws, size_t ws_size,
                              hipStream_t stream) {
    const float* x = (const float*)d_in[0];
    const int* ei = (const int*)d_in[1];
    const float* W1 = (const float*)d_in[2];
    const float* att_src1 = (const float*)d_in[3];
    const float* att_dst1 = (const float*)d_in[4];
    const float* b1 = (const float*)d_in[5];
    const float* W2 = (const float*)d_in[6];
    const float* att_src2 = (const float*)d_in[7];
    const float* att_dst2 = (const float*)d_in[8];
    const float* b2 = (const float*)d_in[9];

    int N = in_sizes[0] / IN_CH;
    int E = in_sizes[1] / 2;

    char* wsp = (char*)d_ws;
    size_t off = 0;
    auto carve = [&](size_t bytes) -> void* {
        void* p = wsp + off;
        off = (off + bytes + 255) & ~(size_t)255;
        return p;
    };
    int nblocks = (E + RB - 1) / RB;

    uint32* packed = (uint32*)carve((size_t)E * 4);
    uint32* tmp = (uint32*)carve((size_t)E * 4);
    int* gcount = (int*)carve(1024);
    int* gbase = (int*)carve(1032);
    int* cursor = (int*)carve(1024);
    int* offsets = (int*)carve((size_t)(N + 1) * 4);
    uint32* h1b = (uint32*)carve((size_t)N * C1 * 2);
    uint32* h2b = (uint32*)carve((size_t)N * OUT_CH * 2);
    uint32* out1h = (uint32*)carve((size_t)N * C1 * 2);
    float* as1 = (float*)carve((size_t)N * HEADS * 4);
    float* ad1 = (float*)carve((size_t)N * HEADS * 4);
    float* as2 = (float*)carve((size_t)N * 4);
    float* ad2 = (float*)carve((size_t)N * 4);

    // ---- CSR build: 4-kernel chain
    int nbuckets = (N + 255) / 256;
    hipMemsetAsync(gcount, 0, 1024, stream);
    pack_hist_kernel<<<nblocks, 256, 0, stream>>>(ei, E, packed, gcount);
    bases_kernel<<<1, 256, 0, stream>>>(gcount, gbase, cursor, E);
    scatter_msd_kernel<<<nblocks, 256, 0, stream>>>(packed, tmp, cursor, E);
    local_sort_kernel<<<nbuckets, 256, 0, stream>>>(tmp, packed, gbase, offsets, N, E);

    int nwaveblocks = (N * 64 + 255) / 256;
    int ngemmblocks = (N + 63) / 64;

    // layer 1
    gemm_dots_kernel<128, 128, 4, false>
        <<<ngemmblocks, 256, 0, stream>>>(x, W1, att_src1, att_dst1, h1b, as1, ad1, N);
    aggregate_kernel<128, 4, true, true>
        <<<nwaveblocks, 256, 0, stream>>>(h1b, as1, ad1, offsets, packed, b1, (void*)out1h, N);

    // layer 2
    gemm_dots_kernel<128, 64, 1, true><<<ngemmblocks, 256, 0, stream>>>(
        (const float*)out1h, W2, att_src2, att_dst2, h2b, as2, ad2, N);
    aggregate_kernel<64, 1, false, false>
        <<<nwaveblocks, 256, 0, stream>>>(h2b, as2, ad2, offsets, packed, b2, d_out, N);
}

// Round 11
// 129.131 us; speedup vs baseline: 1.1881x; 1.1881x over previous
//
#include <hip/hip_runtime.h>

#define NEG_SLOPE 0.2f

typedef unsigned int uint32;
typedef unsigned short ushort;
typedef unsigned long long u64;
typedef __fp16 f16x2 __attribute__((ext_vector_type(2)));
typedef __fp16 half8 __attribute__((ext_vector_type(8)));
typedef float f32x4 __attribute__((ext_vector_type(4)));

constexpr int IN_CH = 128;
constexpr int HID = 32;
constexpr int HEADS = 4;
constexpr int OUT_CH = 64;
constexpr int C1 = HEADS * HID; // 128
constexpr int RB = 1024;        // elements per radix block

__device__ inline uint32 pk_f16(float lo, float hi) {
    f16x2 h = __builtin_amdgcn_cvt_pkrtz(lo, hi);
    uint32 r;
    __builtin_memcpy(&r, &h, 4);
    return r;
}
__device__ inline float f16_lo(uint32 v) {
    f16x2 h;
    __builtin_memcpy(&h, &v, 4);
    return (float)h[0];
}
__device__ inline float f16_hi(uint32 v) {
    f16x2 h;
    __builtin_memcpy(&h, &v, 4);
    return (float)h[1];
}
__device__ inline float leaky(float e) {
    return fmaxf(e, 0.f) + NEG_SLOPE * fminf(e, 0.f);
}

// ========== CSR via MSD-byte scatter (digit = dst>>8) + per-bucket LDS counting sort ==========
// within-dst edge order is arbitrary (only permutes fp summation; tolerance covers it)
// per-(bucket,block) hist columns + scan keep the scatter contention-free (round-10 lesson:
// shared-cursor atomics on 256 counters cost +24 us)

__global__ __launch_bounds__(256) void pack_hist_kernel(const int* __restrict__ ei, int E,
                                                        uint32* __restrict__ packed,
                                                        int* __restrict__ ghist, int nblocks) {
    __shared__ int lh[256];
    int t = threadIdx.x;
    lh[t] = 0;
    __syncthreads();
    int base0 = blockIdx.x * RB;
#pragma unroll
    for (int j = 0; j < 4; j++) {
        int e = base0 + j * 256 + t;
        if (e < E) {
            uint32 s = (uint32)ei[e], d = (uint32)ei[E + e];
            uint32 v = (d << 16) | s;
            packed[e] = v;
            atomicAdd(&lh[v >> 24], 1);
        }
    }
    __syncthreads();
    ghist[(size_t)t * nblocks + blockIdx.x] = lh[t];
}

__global__ __launch_bounds__(256) void gscanA_kernel(int* __restrict__ a, int* __restrict__ bsums,
                                                     int L) {
    __shared__ int tsum[256];
    int t = threadIdx.x;
    int base = blockIdx.x * 2048 + t * 8;
    int v[8];
    int s = 0;
#pragma unroll
    for (int i = 0; i < 8; i++) {
        v[i] = (base + i < L) ? a[base + i] : 0;
        s += v[i];
    }
    tsum[t] = s;
    __syncthreads();
    for (int d = 1; d < 256; d <<= 1) {
        int x = (t >= d) ? tsum[t - d] : 0;
        __syncthreads();
        tsum[t] += x;
        __syncthreads();
    }
    int ex = (t > 0) ? tsum[t - 1] : 0;
    if (t == 255) bsums[blockIdx.x] = tsum[255];
#pragma unroll
    for (int i = 0; i < 8; i++) {
        if (base + i < L) a[base + i] = ex;
        ex += v[i];
    }
}

__global__ void gscanB_kernel(int* __restrict__ bsums, int nb) {
    int lane = threadIdx.x;
    int v0 = (lane < nb) ? bsums[lane] : 0;
    int v1 = (64 + lane < nb) ? bsums[64 + lane] : 0;
    int s0 = v0;
#pragma unroll
    for (int d = 1; d < 64; d <<= 1) {
        int o = __shfl_up(s0, d);
        if (lane >= d) s0 += o;
    }
    int tot0 = __shfl(s0, 63);
    int s1 = v1;
#pragma unroll
    for (int d = 1; d < 64; d <<= 1) {
        int o = __shfl_up(s1, d);
        if (lane >= d) s1 += o;
    }
    s1 += tot0;
    if (lane < nb) bsums[lane] = s0 - v0;
    if (64 + lane < nb) bsums[64 + lane] = s1 - v1;
}

__global__ void gscanC_kernel(int* __restrict__ a, const int* __restrict__ bsums, int L) {
    int i = blockIdx.x * blockDim.x + threadIdx.x;
    if (i < L) a[i] += bsums[i / 2048];
}

__global__ __launch_bounds__(256) void scatter_msd_kernel(const uint32* __restrict__ in,
                                                          uint32* __restrict__ out,
                                                          const int* __restrict__ gbase, int E,
                                                          int nblocks) {
    __shared__ int lbase[256];
    int t = threadIdx.x;
    lbase[t] = gbase[(size_t)t * nblocks + blockIdx.x];
    __syncthreads();
    int base0 = blockIdx.x * RB;
#pragma unroll
    for (int j = 0; j < 4; j++) {
        int e = base0 + j * 256 + t;
        if (e < E) {
            uint32 v = in[e];
            int slot = atomicAdd(&lbase[v >> 24], 1);
            out[slot] = v;
        }
    }
}

// one block per 256-dst bucket: counting sort by (dst & 0xff) + emit offsets[]
__global__ __launch_bounds__(256) void local_sort_kernel(const uint32* __restrict__ in,
                                                         uint32* __restrict__ out,
                                                         const int* __restrict__ ghist, int nblocks,
                                                         int* __restrict__ offsets, int N, int E) {
    __shared__ int hist[256];
    __shared__ int cum[256];
    int b = blockIdx.x;
    int t = threadIdx.x;
    int segstart = ghist[(size_t)b * nblocks];
    int segend = (b + 1 < 256) ? ghist[(size_t)(b + 1) * nblocks] : E;
    hist[t] = 0;
    __syncthreads();
    for (int i = segstart + t; i < segend; i += 256) atomicAdd(&hist[(in[i] >> 16) & 0xff], 1);
    __syncthreads();
    int v = hist[t];
    cum[t] = v;
    __syncthreads();
    for (int d = 1; d < 256; d <<= 1) {
        int x = (t >= d) ? cum[t - d] : 0;
        __syncthreads();
        cum[t] += x;
        __syncthreads();
    }
    int myExcl = cum[t] - v;
    int dstv = b * 256 + t;
    if (dstv < N) offsets[dstv] = segstart + myExcl;
    if (b == 0 && t == 0) offsets[N] = E;
    hist[t] = myExcl;
    __syncthreads();
    for (int i = segstart + t; i < segend; i += 256) {
        uint32 w = in[i];
        int slot = atomicAdd(&hist[(w >> 16) & 0xff], 1);
        out[segstart + slot] = w;
    }
}

// ---------------- MFMA f16 GEMM + attention dots + f16 pack ----------------
// BM=64 rows/block, whole K=128 staged once. 4 waves, wave w -> rows w*16..+15.
// A frag: lane l holds A[l&15][(l>>4)*8+j]; B frag: B[(l>>4)*8+j][l&15] via wt[col][k].
// D: col=lane&15, row=(lane>>4)*4+reg (m89-verified mapping).

template <int K, int COLS, int H, bool AF16>
__global__ __launch_bounds__(256) void gemm_dots_kernel(
    const float* __restrict__ A, const float* __restrict__ W,
    const float* __restrict__ att_s, const float* __restrict__ att_d,
    uint32* __restrict__ hb, float* __restrict__ as_, float* __restrict__ ad_, int N) {
    static_assert(K == 128, "");
    constexpr int CF = COLS / 16;
    __shared__ ushort xs[64][136];
    __shared__ ushort wt[COLS][136];
    int tid = threadIdx.x;
    int row0 = blockIdx.x * 64;

#pragma unroll
    for (int l = 0; l < 4; l++) {
        int idx = tid + l * 256;
        int row = idx >> 4, kc = idx & 15;
        uint4 pkv = make_uint4(0, 0, 0, 0);
        if (row0 + row < N) {
            if constexpr (AF16) {
                pkv = *(const uint4*)((const uint32*)A + (size_t)(row0 + row) * (K / 2) + kc * 4);
            } else {
                const float* ap = A + (size_t)(row0 + row) * K + kc * 8;
                float4 v0 = *(const float4*)ap;
                float4 v1 = *(const float4*)(ap + 4);
                pkv = make_uint4(pk_f16(v0.x, v0.y), pk_f16(v0.z, v0.w), pk_f16(v1.x, v1.y),
                                 pk_f16(v1.z, v1.w));
            }
        }
        *(uint4*)&xs[row][kc * 8] = pkv;
    }
    constexpr int NP = (K / 2) * COLS / 256;
#pragma unroll
    for (int l = 0; l < NP; l++) {
        int p = tid + l * 256;
        int col = p % COLS, kp = p / COLS;
        float v0 = W[(size_t)(2 * kp) * COLS + col];
        float v1 = W[(size_t)(2 * kp + 1) * COLS + col];
        *(uint32*)&wt[col][kp * 2] = pk_f16(v0, v1);
    }
    __syncthreads();

    int w = tid >> 6, l = tid & 63;
    int q = l & 15, g = l >> 4;

    half8 af[4];
#pragma unroll
    for (int ks = 0; ks < 4; ks++) af[ks] = *(const half8*)&xs[w * 16 + q][ks * 32 + g * 8];

    f32x4 accs[CF];
#pragma unroll
    for (int cf = 0; cf < CF; cf++) {
        f32x4 a = {0.f, 0.f, 0.f, 0.f};
#pragma unroll
        for (int ks = 0; ks < 4; ks++) {
            half8 bf = *(const half8*)&wt[cf * 16 + q][ks * 32 + g * 8];
            a = __builtin_amdgcn_mfma_f32_16x16x32_f16(af[ks], bf, a, 0, 0, 0);
        }
        accs[cf] = a;
    }

    float asf[CF], adf[CF];
#pragma unroll
    for (int cf = 0; cf < CF; cf++) {
        asf[cf] = att_s[cf * 16 + q];
        adf[cf] = att_d[cf * 16 + q];
    }

#pragma unroll
    for (int r = 0; r < 4; r++) {
        int n_r = row0 + w * 16 + g * 4 + r;
        uint32 dw[CF];
        float p0 = 0.f, p1 = 0.f, p2 = 0.f, p3 = 0.f;
        float d0 = 0.f, d1 = 0.f, d2 = 0.f, d3 = 0.f;
#pragma unroll
        for (int cf = 0; cf < CF; cf++) {
            float v = accs[cf][r];
            float nb = __shfl_xor(v, 1);
            float ev = (q & 1) ? nb : v;
            float ov = (q & 1) ? v : nb;
            dw[cf] = pk_f16(ev, ov);
            float cs = v * asf[cf], cd = v * adf[cf];
            if constexpr (H == 4) {
                if (cf < 2) {
                    p0 += cs;
                    d0 += cd;
                } else if (cf < 4) {
                    p1 += cs;
                    d1 += cd;
                } else if (cf < 6) {
                    p2 += cs;
                    d2 += cd;
                } else {
                    p3 += cs;
                    d3 += cd;
                }
            } else {
                p0 += cs;
                d0 += cd;
            }
        }
#pragma unroll
        for (int dd = 1; dd < 16; dd <<= 1) {
            p0 += __shfl_xor(p0, dd);
            d0 += __shfl_xor(d0, dd);
            if constexpr (H == 4) {
                p1 += __shfl_xor(p1, dd);
                d1 += __shfl_xor(d1, dd);
                p2 += __shfl_xor(p2, dd);
                d2 += __shfl_xor(d2, dd);
                p3 += __shfl_xor(p3, dd);
                d3 += __shfl_xor(d3, dd);
            }
        }
        if (n_r < N) {
            if ((q & 1) == 0) {
                uint32* hp = hb + (size_t)n_r * (COLS / 2) + (q >> 1);
#pragma unroll
                for (int cf = 0; cf < CF; cf++) hp[cf * 8] = dw[cf];
            }
            if constexpr (H == 4) {
                if ((q >> 2) == r) {
                    int hh = q & 3;
                    float vs = hh == 0 ? p0 : hh == 1 ? p1 : hh == 2 ? p2 : p3;
                    float vd = hh == 0 ? d0 : hh == 1 ? d1 : hh == 2 ? d2 : d3;
                    as_[(size_t)n_r * 4 + hh] = vs;
                    ad_[(size_t)n_r * 4 + hh] = vd;
                }
            } else {
                if (q == r) {
                    as_[n_r] = p0;
                    ad_[n_r] = d0;
                }
            }
        }
    }
}

// ---------------- fused single-pass segment softmax + aggregation ----------------

template <int C, int H, bool RELU, bool OUTF16>
__global__ __launch_bounds__(256) void aggregate_kernel(
    const uint32* __restrict__ hb, const float* __restrict__ as_,
    const float* __restrict__ ad_, const int* __restrict__ offsets,
    const uint32* __restrict__ csr, const float* __restrict__ bias, void* __restrict__ outp,
    int N) {
    __shared__ float plds[4][64 * H];
    __shared__ int slds[4][64];
    int gid = blockIdx.x * blockDim.x + threadIdx.x;
    int n = gid >> 6;
    int lane = threadIdx.x & 63;
    int wslot = threadIdx.x >> 6;
    if (n >= N) return;
    int off = offsets[n];
    int deg = offsets[n + 1] - off;

    float ad[H], s[H];
#pragma unroll
    for (int h = 0; h < H; h++) {
        ad[h] = ad_[(size_t)n * H + h];
        s[h] = 0.f;
    }

    constexpr int G = C / 8;
    constexpr int EPI = 64 / G;
    int eg = lane / G;
    int cl = lane % G;
    int hsel = (H == 4) ? (cl >> 2) : 0;
    float acc[8];
#pragma unroll
    for (int j = 0; j < 8; j++) acc[j] = 0.f;

    for (int base = 0; base <= deg; base += 64) {
        int my = base + lane;
        int cnt = min(64, deg + 1 - base);
        if (my <= deg) {
            int si = (my < deg) ? (int)(csr[off + my] & 0xffffu) : n;
            slds[wslot][lane] = si;
            if constexpr (H == 4) {
                float4 a = ((const float4*)as_)[si];
                float q0 = __expf(fminf(leaky(a.x + ad[0]), 80.f));
                float q1 = __expf(fminf(leaky(a.y + ad[1]), 80.f));
                float q2 = __expf(fminf(leaky(a.z + ad[2]), 80.f));
                float q3 = __expf(fminf(leaky(a.w + ad[3]), 80.f));
                s[0] += q0;
                s[1] += q1;
                s[2] += q2;
                s[3] += q3;
                ((float4*)plds[wslot])[lane] = make_float4(q0, q1, q2, q3);
            } else {
                float p = __expf(fminf(leaky(as_[si] + ad[0]), 80.f));
                s[0] += p;
                plds[wslot][lane] = p;
            }
        }
        int t2 = 0;
        for (; t2 + 2 * EPI <= cnt; t2 += 2 * EPI) {
            int tA = t2 + eg, tB = t2 + EPI + eg;
            int srcA = slds[wslot][tA];
            int srcB = slds[wslot][tB];
            float alA = plds[wslot][tA * H + hsel];
            float alB = plds[wslot][tB * H + hsel];
            uint4 uA = *(const uint4*)(hb + (size_t)srcA * (C / 2) + cl * 4);
            uint4 uB = *(const uint4*)(hb + (size_t)srcB * (C / 2) + cl * 4);
            acc[0] = fmaf(alA, f16_lo(uA.x), acc[0]);
            acc[1] = fmaf(alA, f16_hi(uA.x), acc[1]);
            acc[2] = fmaf(alA, f16_lo(uA.y), acc[2]);
            acc[3] = fmaf(alA, f16_hi(uA.y), acc[3]);
            acc[4] = fmaf(alA, f16_lo(uA.z), acc[4]);
            acc[5] = fmaf(alA, f16_hi(uA.z), acc[5]);
            acc[6] = fmaf(alA, f16_lo(uA.w), acc[6]);
            acc[7] = fmaf(alA, f16_hi(uA.w), acc[7]);
            acc[0] = fmaf(alB, f16_lo(uB.x), acc[0]);
            acc[1] = fmaf(alB, f16_hi(uB.x), acc[1]);
            acc[2] = fmaf(alB, f16_lo(uB.y), acc[2]);
            acc[3] = fmaf(alB, f16_hi(uB.y), acc[3]);
            acc[4] = fmaf(alB, f16_lo(uB.z), acc[4]);
            acc[5] = fmaf(alB, f16_hi(uB.z), acc[5]);
            acc[6] = fmaf(alB, f16_lo(uB.w), acc[6]);
            acc[7] = fmaf(alB, f16_hi(uB.w), acc[7]);
        }
        for (; t2 < cnt; t2 += EPI) {
            int te = t2 + eg;
            bool valid = te < cnt;
            int tc = valid ? te : 0;
            int src = slds[wslot][tc];
            float al = plds[wslot][tc * H + hsel];
            al = valid ? al : 0.f;
            uint4 u = *(const uint4*)(hb + (size_t)src * (C / 2) + cl * 4);
            acc[0] = fmaf(al, f16_lo(u.x), acc[0]);
            acc[1] = fmaf(al, f16_hi(u.x), acc[1]);
            acc[2] = fmaf(al, f16_lo(u.y), acc[2]);
            acc[3] = fmaf(al, f16_hi(u.y), acc[3]);
            acc[4] = fmaf(al, f16_lo(u.z), acc[4]);
            acc[5] = fmaf(al, f16_hi(u.z), acc[5]);
            acc[6] = fmaf(al, f16_lo(u.w), acc[6]);
            acc[7] = fmaf(al, f16_hi(u.w), acc[7]);
        }
    }

#pragma unroll
    for (int d = 1; d < 64; d <<= 1)
#pragma unroll
        for (int h = 0; h < H; h++) s[h] += __shfl_xor(s[h], d);
#pragma unroll
    for (int d = G; d < 64; d <<= 1)
#pragma unroll
        for (int j = 0; j < 8; j++) acc[j] += __shfl_xor(acc[j], d);

    if (eg == 0) {
        float inv = 1.f / s[hsel];
        int c = cl * 8;
        float o[8];
#pragma unroll
        for (int j = 0; j < 8; j++) {
            o[j] = fmaf(acc[j], inv, bias[c + j]);
            if (RELU) o[j] = fmaxf(o[j], 0.f);
        }
        if constexpr (OUTF16) {
            uint4 pkv = make_uint4(pk_f16(o[0], o[1]), pk_f16(o[2], o[3]), pk_f16(o[4], o[5]),
                                   pk_f16(o[6], o[7]));
            *(uint4*)((uint32*)outp + (size_t)n * (C / 2) + cl * 4) = pkv;
        } else {
            float* out = (float*)outp;
            *(float4*)(out + (size_t)n * C + c) = make_float4(o[0], o[1], o[2], o[3]);
            *(float4*)(out + (size_t)n * C + c + 4) = make_float4(o[4], o[5], o[6], o[7]);
        }
    }
}

// ---------------- launch ----------------

extern "C" void kernel_launch(void* const* d_in, const int* in_sizes, int n_in,
                              void* d_out, int out_size, void* d_ws, size_t ws_size,
                              hipStream_t stream) {
    const float* x = (const float*)d_in[0];
    const int* ei = (const int*)d_in[1];
    const float* W1 = (const float*)d_in[2];
    const float* att_src1 = (const float*)d_in[3];
    const float* att_dst1 = (const float*)d_in[4];
    const float* b1 = (const float*)d_in[5];
    const float* W2 = (const float*)d_in[6];
    const float* att_src2 = (const float*)d_in[7];
    const float* att_dst2 = (const float*)d_in[8];
    const float* b2 = (const float*)d_in[9];

    int N = in_sizes[0] / IN_CH;
    int E = in_sizes[1] / 2;

    char* wsp = (char*)d_ws;
    size_t off = 0;
    auto carve = [&](size_t bytes) -> void* {
        void* p = wsp + off;
        off = (off + bytes + 255) & ~(size_t)255;
        return p;
    };
    int nblocks = (E + RB - 1) / RB;
    int L = 256 * nblocks;
    int nsb = (L + 2047) / 2048;

    uint32* packed = (uint32*)carve((size_t)E * 4);
    uint32* tmp = (uint32*)carve((size_t)E * 4);
    int* ghist = (int*)carve((size_t)L * 4);
    int* bsums = (int*)carve(4096);
    int* offsets = (int*)carve((size_t)(N + 1) * 4);
    uint32* h1b = (uint32*)carve((size_t)N * C1 * 2);
    uint32* h2b = (uint32*)carve((size_t)N * OUT_CH * 2);
    uint32* out1h = (uint32*)carve((size_t)N * C1 * 2);
    float* as1 = (float*)carve((size_t)N * HEADS * 4);
    float* ad1 = (float*)carve((size_t)N * HEADS * 4);
    float* as2 = (float*)carve((size_t)N * 4);
    float* ad2 = (float*)carve((size_t)N * 4);

    // ---- CSR build: MSD-byte scatter + per-bucket LDS counting sort
    int nbuckets = (N + 255) / 256;
    pack_hist_kernel<<<nblocks, 256, 0, stream>>>(ei, E, packed, ghist, nblocks);
    gscanA_kernel<<<nsb, 256, 0, stream>>>(ghist, bsums, L);
    gscanB_kernel<<<1, 64, 0, stream>>>(bsums, nsb);
    gscanC_kernel<<<(L + 255) / 256, 256, 0, stream>>>(ghist, bsums, L);
    scatter_msd_kernel<<<nblocks, 256, 0, stream>>>(packed, tmp, ghist, E, nblocks);
    local_sort_kernel<<<nbuckets, 256, 0, stream>>>(tmp, packed, ghist, nblocks, offsets, N, E);

    int nwaveblocks = (N * 64 + 255) / 256;
    int ngemmblocks = (N + 63) / 64;

    // layer 1
    gemm_dots_kernel<128, 128, 4, false>
        <<<ngemmblocks, 256, 0, stream>>>(x, W1, att_src1, att_dst1, h1b, as1, ad1, N);
    aggregate_kernel<128, 4, true, true>
        <<<nwaveblocks, 256, 0, stream>>>(h1b, as1, ad1, offsets, packed, b1, (void*)out1h, N);

    // layer 2
    gemm_dots_kernel<128, 64, 1, true><<<ngemmblocks, 256, 0, stream>>>(
        (const float*)out1h, W2, att_src2, att_dst2, h2b, as2, ad2, N);
    aggregate_kernel<64, 1, false, false>
        <<<nwaveblocks, 256, 0, stream>>>(h2b, as2, ad2, offsets, packed, b2, d_out, N);
}

// Round 12
// 126.668 us; speedup vs baseline: 1.2112x; 1.0194x over previous
//
#include <hip/hip_runtime.h>

#define NEG_SLOPE 0.2f

typedef unsigned int uint32;
typedef unsigned short ushort;
typedef unsigned long long u64;
typedef __fp16 f16x2 __attribute__((ext_vector_type(2)));
typedef __fp16 half8 __attribute__((ext_vector_type(8)));
typedef float f32x4 __attribute__((ext_vector_type(4)));

constexpr int IN_CH = 128;
constexpr int HID = 32;
constexpr int HEADS = 4;
constexpr int OUT_CH = 64;
constexpr int C1 = HEADS * HID; // 128
constexpr int RB = 1024;        // elements per radix block

__device__ inline uint32 pk_f16(float lo, float hi) {
    f16x2 h = __builtin_amdgcn_cvt_pkrtz(lo, hi);
    uint32 r;
    __builtin_memcpy(&r, &h, 4);
    return r;
}
__device__ inline float f16_lo(uint32 v) {
    f16x2 h;
    __builtin_memcpy(&h, &v, 4);
    return (float)h[0];
}
__device__ inline float f16_hi(uint32 v) {
    f16x2 h;
    __builtin_memcpy(&h, &v, 4);
    return (float)h[1];
}
__device__ inline float leaky(float e) {
    return fmaxf(e, 0.f) + NEG_SLOPE * fminf(e, 0.f);
}

// ========== CSR via MSD-byte scatter (digit = dst>>8) + per-bucket LDS counting sort ==========
// within-dst edge order is arbitrary (only permutes fp summation; tolerance covers it)
// per-(bucket,block) hist columns + scan keep the scatter contention-free (round-10 lesson:
// shared-cursor atomics on 256 counters cost +24 us)

__global__ __launch_bounds__(256) void pack_hist_kernel(const int* __restrict__ ei, int E,
                                                        uint32* __restrict__ packed,
                                                        int* __restrict__ ghist, int nblocks) {
    __shared__ int lh[256];
    int t = threadIdx.x;
    lh[t] = 0;
    __syncthreads();
    int base0 = blockIdx.x * RB;
#pragma unroll
    for (int j = 0; j < 4; j++) {
        int e = base0 + j * 256 + t;
        if (e < E) {
            uint32 s = (uint32)ei[e], d = (uint32)ei[E + e];
            uint32 v = (d << 16) | s;
            packed[e] = v;
            atomicAdd(&lh[v >> 24], 1);
        }
    }
    __syncthreads();
    ghist[(size_t)t * nblocks + blockIdx.x] = lh[t];
}

// one block per bucket: exclusive scan of ghist row (along blocks), emit bucket total
__global__ __launch_bounds__(256) void rowscan_kernel(int* __restrict__ ghist,
                                                      int* __restrict__ totals, int nblocks) {
    __shared__ int ts[256];
    int b = blockIdx.x, t = threadIdx.x;
    int per = (nblocks + 255) >> 8;
    int* row = ghist + (size_t)b * nblocks;
    int v[8];
    int s = 0;
#pragma unroll
    for (int i = 0; i < 8; i++) {
        int idx = t * per + i;
        v[i] = (i < per && idx < nblocks) ? row[idx] : 0;
        s += v[i];
    }
    ts[t] = s;
    __syncthreads();
    for (int d = 1; d < 256; d <<= 1) {
        int x = (t >= d) ? ts[t - d] : 0;
        __syncthreads();
        ts[t] += x;
        __syncthreads();
    }
    int ex = (t > 0) ? ts[t - 1] : 0;
    if (t == 255) totals[b] = ts[255];
#pragma unroll
    for (int i = 0; i < 8; i++) {
        int idx = t * per + i;
        if (i < per && idx < nblocks) row[idx] = ex;
        ex += v[i];
    }
}

// single block: exclusive scan of 256 bucket totals -> gbase[257]
__global__ __launch_bounds__(256) void bases_kernel(const int* __restrict__ totals,
                                                    int* __restrict__ gbase, int E) {
    __shared__ int cum[256];
    int t = threadIdx.x;
    int v = totals[t];
    cum[t] = v;
    __syncthreads();
    for (int d = 1; d < 256; d <<= 1) {
        int x = (t >= d) ? cum[t - d] : 0;
        __syncthreads();
        cum[t] += x;
        __syncthreads();
    }
    gbase[t] = cum[t] - v;
    if (t == 255) gbase[256] = E;
}

__global__ __launch_bounds__(256) void scatter_msd_kernel(const uint32* __restrict__ in,
                                                          uint32* __restrict__ out,
                                                          const int* __restrict__ ghist,
                                                          const int* __restrict__ gbase, int E,
                                                          int nblocks) {
    __shared__ int lbase[256];
    int t = threadIdx.x;
    lbase[t] = ghist[(size_t)t * nblocks + blockIdx.x] + gbase[t];
    __syncthreads();
    int base0 = blockIdx.x * RB;
#pragma unroll
    for (int j = 0; j < 4; j++) {
        int e = base0 + j * 256 + t;
        if (e < E) {
            uint32 v = in[e];
            int slot = atomicAdd(&lbase[v >> 24], 1);
            out[slot] = v;
        }
    }
}

// one block per 256-dst bucket: counting sort by (dst & 0xff) + emit offsets[]
__global__ __launch_bounds__(256) void local_sort_kernel(const uint32* __restrict__ in,
                                                         uint32* __restrict__ out,
                                                         const int* __restrict__ gbase,
                                                         int* __restrict__ offsets, int N, int E) {
    __shared__ int hist[256];
    __shared__ int cum[256];
    int b = blockIdx.x;
    int t = threadIdx.x;
    int segstart = gbase[b];
    int segend = gbase[b + 1];
    hist[t] = 0;
    __syncthreads();
    for (int i = segstart + t; i < segend; i += 256) atomicAdd(&hist[(in[i] >> 16) & 0xff], 1);
    __syncthreads();
    int v = hist[t];
    cum[t] = v;
    __syncthreads();
    for (int d = 1; d < 256; d <<= 1) {
        int x = (t >= d) ? cum[t - d] : 0;
        __syncthreads();
        cum[t] += x;
        __syncthreads();
    }
    int myExcl = cum[t] - v;
    int dstv = b * 256 + t;
    if (dstv < N) offsets[dstv] = segstart + myExcl;
    if (b == 0 && t == 0) offsets[N] = E;
    hist[t] = myExcl;
    __syncthreads();
    for (int i = segstart + t; i < segend; i += 256) {
        uint32 w = in[i];
        int slot = atomicAdd(&hist[(w >> 16) & 0xff], 1);
        out[segstart + slot] = w;
    }
}

// ---------------- MFMA f16 GEMM + attention dots + f16 pack ----------------
// BM=64 rows/block, whole K=128 staged once. 4 waves, wave w -> rows w*16..+15.
// A frag: lane l holds A[l&15][(l>>4)*8+j]; B frag: B[(l>>4)*8+j][l&15] via wt[col][k].
// D: col=lane&15, row=(lane>>4)*4+reg (m89-verified mapping).

template <int K, int COLS, int H, bool AF16>
__global__ __launch_bounds__(256) void gemm_dots_kernel(
    const float* __restrict__ A, const float* __restrict__ W,
    const float* __restrict__ att_s, const float* __restrict__ att_d,
    uint32* __restrict__ hb, float* __restrict__ as_, float* __restrict__ ad_, int N) {
    static_assert(K == 128, "");
    constexpr int CF = COLS / 16;
    __shared__ ushort xs[64][136];
    __shared__ ushort wt[COLS][136];
    int tid = threadIdx.x;
    int row0 = blockIdx.x * 64;

#pragma unroll
    for (int l = 0; l < 4; l++) {
        int idx = tid + l * 256;
        int row = idx >> 4, kc = idx & 15;
        uint4 pkv = make_uint4(0, 0, 0, 0);
        if (row0 + row < N) {
            if constexpr (AF16) {
                pkv = *(const uint4*)((const uint32*)A + (size_t)(row0 + row) * (K / 2) + kc * 4);
            } else {
                const float* ap = A + (size_t)(row0 + row) * K + kc * 8;
                float4 v0 = *(const float4*)ap;
                float4 v1 = *(const float4*)(ap + 4);
                pkv = make_uint4(pk_f16(v0.x, v0.y), pk_f16(v0.z, v0.w), pk_f16(v1.x, v1.y),
                                 pk_f16(v1.z, v1.w));
            }
        }
        *(uint4*)&xs[row][kc * 8] = pkv;
    }
    constexpr int NP = (K / 2) * COLS / 256;
#pragma unroll
    for (int l = 0; l < NP; l++) {
        int p = tid + l * 256;
        int col = p % COLS, kp = p / COLS;
        float v0 = W[(size_t)(2 * kp) * COLS + col];
        float v1 = W[(size_t)(2 * kp + 1) * COLS + col];
        *(uint32*)&wt[col][kp * 2] = pk_f16(v0, v1);
    }
    __syncthreads();

    int w = tid >> 6, l = tid & 63;
    int q = l & 15, g = l >> 4;

    half8 af[4];
#pragma unroll
    for (int ks = 0; ks < 4; ks++) af[ks] = *(const half8*)&xs[w * 16 + q][ks * 32 + g * 8];

    f32x4 accs[CF];
#pragma unroll
    for (int cf = 0; cf < CF; cf++) {
        f32x4 a = {0.f, 0.f, 0.f, 0.f};
#pragma unroll
        for (int ks = 0; ks < 4; ks++) {
            half8 bf = *(const half8*)&wt[cf * 16 + q][ks * 32 + g * 8];
            a = __builtin_amdgcn_mfma_f32_16x16x32_f16(af[ks], bf, a, 0, 0, 0);
        }
        accs[cf] = a;
    }

    float asf[CF], adf[CF];
#pragma unroll
    for (int cf = 0; cf < CF; cf++) {
        asf[cf] = att_s[cf * 16 + q];
        adf[cf] = att_d[cf * 16 + q];
    }

#pragma unroll
    for (int r = 0; r < 4; r++) {
        int n_r = row0 + w * 16 + g * 4 + r;
        uint32 dw[CF];
        float p0 = 0.f, p1 = 0.f, p2 = 0.f, p3 = 0.f;
        float d0 = 0.f, d1 = 0.f, d2 = 0.f, d3 = 0.f;
#pragma unroll
        for (int cf = 0; cf < CF; cf++) {
            float v = accs[cf][r];
            float nb = __shfl_xor(v, 1);
            float ev = (q & 1) ? nb : v;
            float ov = (q & 1) ? v : nb;
            dw[cf] = pk_f16(ev, ov);
            float cs = v * asf[cf], cd = v * adf[cf];
            if constexpr (H == 4) {
                if (cf < 2) {
                    p0 += cs;
                    d0 += cd;
                } else if (cf < 4) {
                    p1 += cs;
                    d1 += cd;
                } else if (cf < 6) {
                    p2 += cs;
                    d2 += cd;
                } else {
                    p3 += cs;
                    d3 += cd;
                }
            } else {
                p0 += cs;
                d0 += cd;
            }
        }
#pragma unroll
        for (int dd = 1; dd < 16; dd <<= 1) {
            p0 += __shfl_xor(p0, dd);
            d0 += __shfl_xor(d0, dd);
            if constexpr (H == 4) {
                p1 += __shfl_xor(p1, dd);
                d1 += __shfl_xor(d1, dd);
                p2 += __shfl_xor(p2, dd);
                d2 += __shfl_xor(d2, dd);
                p3 += __shfl_xor(p3, dd);
                d3 += __shfl_xor(d3, dd);
            }
        }
        if (n_r < N) {
            if ((q & 1) == 0) {
                uint32* hp = hb + (size_t)n_r * (COLS / 2) + (q >> 1);
#pragma unroll
                for (int cf = 0; cf < CF; cf++) hp[cf * 8] = dw[cf];
            }
            if constexpr (H == 4) {
                if ((q >> 2) == r) {
                    int hh = q & 3;
                    float vs = hh == 0 ? p0 : hh == 1 ? p1 : hh == 2 ? p2 : p3;
                    float vd = hh == 0 ? d0 : hh == 1 ? d1 : hh == 2 ? d2 : d3;
                    as_[(size_t)n_r * 4 + hh] = vs;
                    ad_[(size_t)n_r * 4 + hh] = vd;
                }
            } else {
                if (q == r) {
                    as_[n_r] = p0;
                    ad_[n_r] = d0;
                }
            }
        }
    }
}

// ---------------- fused single-pass segment softmax + aggregation ----------------
// XCD-bijective block swizzle (m204): consecutive dst ranges stay on one XCD so
// csr/offsets cachelines are fetched by a single XCD's L2.

template <int C, int H, bool RELU, bool OUTF16>
__global__ __launch_bounds__(256) void aggregate_kernel(
    const uint32* __restrict__ hb, const float* __restrict__ as_,
    const float* __restrict__ ad_, const int* __restrict__ offsets,
    const uint32* __restrict__ csr, const float* __restrict__ bias, void* __restrict__ outp,
    int N) {
    __shared__ float plds[4][64 * H];
    __shared__ int slds[4][64];
    int bid = blockIdx.x;
    int nwg = gridDim.x;
    int qq = nwg >> 3, rr = nwg & 7;
    int xcd = bid & 7, jj = bid >> 3;
    int work = (xcd < rr ? xcd * (qq + 1) : rr * (qq + 1) + (xcd - rr) * qq) + jj;
    int lane = threadIdx.x & 63;
    int wslot = threadIdx.x >> 6;
    int n = work * 4 + wslot;
    if (n >= N) return;
    int off = offsets[n];
    int deg = offsets[n + 1] - off;

    float ad[H], s[H];
#pragma unroll
    for (int h = 0; h < H; h++) {
        ad[h] = ad_[(size_t)n * H + h];
        s[h] = 0.f;
    }

    constexpr int G = C / 8;
    constexpr int EPI = 64 / G;
    int eg = lane / G;
    int cl = lane % G;
    int hsel = (H == 4) ? (cl >> 2) : 0;
    float acc[8];
#pragma unroll
    for (int j = 0; j < 8; j++) acc[j] = 0.f;

    for (int base = 0; base <= deg; base += 64) {
        int my = base + lane;
        int cnt = min(64, deg + 1 - base);
        if (my <= deg) {
            int si = (my < deg) ? (int)(csr[off + my] & 0xffffu) : n;
            slds[wslot][lane] = si;
            if constexpr (H == 4) {
                float4 a = ((const float4*)as_)[si];
                float q0 = __expf(fminf(leaky(a.x + ad[0]), 80.f));
                float q1 = __expf(fminf(leaky(a.y + ad[1]), 80.f));
                float q2 = __expf(fminf(leaky(a.z + ad[2]), 80.f));
                float q3 = __expf(fminf(leaky(a.w + ad[3]), 80.f));
                s[0] += q0;
                s[1] += q1;
                s[2] += q2;
                s[3] += q3;
                ((float4*)plds[wslot])[lane] = make_float4(q0, q1, q2, q3);
            } else {
                float p = __expf(fminf(leaky(as_[si] + ad[0]), 80.f));
                s[0] += p;
                plds[wslot][lane] = p;
            }
        }
        int t2 = 0;
        for (; t2 + 2 * EPI <= cnt; t2 += 2 * EPI) {
            int tA = t2 + eg, tB = t2 + EPI + eg;
            int srcA = slds[wslot][tA];
            int srcB = slds[wslot][tB];
            float alA = plds[wslot][tA * H + hsel];
            float alB = plds[wslot][tB * H + hsel];
            uint4 uA = *(const uint4*)(hb + (size_t)srcA * (C / 2) + cl * 4);
            uint4 uB = *(const uint4*)(hb + (size_t)srcB * (C / 2) + cl * 4);
            acc[0] = fmaf(alA, f16_lo(uA.x), acc[0]);
            acc[1] = fmaf(alA, f16_hi(uA.x), acc[1]);
            acc[2] = fmaf(alA, f16_lo(uA.y), acc[2]);
            acc[3] = fmaf(alA, f16_hi(uA.y), acc[3]);
            acc[4] = fmaf(alA, f16_lo(uA.z), acc[4]);
            acc[5] = fmaf(alA, f16_hi(uA.z), acc[5]);
            acc[6] = fmaf(alA, f16_lo(uA.w), acc[6]);
            acc[7] = fmaf(alA, f16_hi(uA.w), acc[7]);
            acc[0] = fmaf(alB, f16_lo(uB.x), acc[0]);
            acc[1] = fmaf(alB, f16_hi(uB.x), acc[1]);
            acc[2] = fmaf(alB, f16_lo(uB.y), acc[2]);
            acc[3] = fmaf(alB, f16_hi(uB.y), acc[3]);
            acc[4] = fmaf(alB, f16_lo(uB.z), acc[4]);
            acc[5] = fmaf(alB, f16_hi(uB.z), acc[5]);
            acc[6] = fmaf(alB, f16_lo(uB.w), acc[6]);
            acc[7] = fmaf(alB, f16_hi(uB.w), acc[7]);
        }
        for (; t2 < cnt; t2 += EPI) {
            int te = t2 + eg;
            bool valid = te < cnt;
            int tc = valid ? te : 0;
            int src = slds[wslot][tc];
            float al = plds[wslot][tc * H + hsel];
            al = valid ? al : 0.f;
            uint4 u = *(const uint4*)(hb + (size_t)src * (C / 2) + cl * 4);
            acc[0] = fmaf(al, f16_lo(u.x), acc[0]);
            acc[1] = fmaf(al, f16_hi(u.x), acc[1]);
            acc[2] = fmaf(al, f16_lo(u.y), acc[2]);
            acc[3] = fmaf(al, f16_hi(u.y), acc[3]);
            acc[4] = fmaf(al, f16_lo(u.z), acc[4]);
            acc[5] = fmaf(al, f16_hi(u.z), acc[5]);
            acc[6] = fmaf(al, f16_lo(u.w), acc[6]);
            acc[7] = fmaf(al, f16_hi(u.w), acc[7]);
        }
    }

#pragma unroll
    for (int d = 1; d < 64; d <<= 1)
#pragma unroll
        for (int h = 0; h < H; h++) s[h] += __shfl_xor(s[h], d);
#pragma unroll
    for (int d = G; d < 64; d <<= 1)
#pragma unroll
        for (int j = 0; j < 8; j++) acc[j] += __shfl_xor(acc[j], d);

    if (eg == 0) {
        float inv = 1.f / s[hsel];
        int c = cl * 8;
        float o[8];
#pragma unroll
        for (int j = 0; j < 8; j++) {
            o[j] = fmaf(acc[j], inv, bias[c + j]);
            if (RELU) o[j] = fmaxf(o[j], 0.f);
        }
        if constexpr (OUTF16) {
            uint4 pkv = make_uint4(pk_f16(o[0], o[1]), pk_f16(o[2], o[3]), pk_f16(o[4], o[5]),
                                   pk_f16(o[6], o[7]));
            *(uint4*)((uint32*)outp + (size_t)n * (C / 2) + cl * 4) = pkv;
        } else {
            float* out = (float*)outp;
            *(float4*)(out + (size_t)n * C + c) = make_float4(o[0], o[1], o[2], o[3]);
            *(float4*)(out + (size_t)n * C + c + 4) = make_float4(o[4], o[5], o[6], o[7]);
        }
    }
}

// ---------------- launch ----------------

extern "C" void kernel_launch(void* const* d_in, const int* in_sizes, int n_in,
                              void* d_out, int out_size, void* d_ws, size_t ws_size,
                              hipStream_t stream) {
    const float* x = (const float*)d_in[0];
    const int* ei = (const int*)d_in[1];
    const float* W1 = (const float*)d_in[2];
    const float* att_src1 = (const float*)d_in[3];
    const float* att_dst1 = (const float*)d_in[4];
    const float* b1 = (const float*)d_in[5];
    const float* W2 = (const float*)d_in[6];
    const float* att_src2 = (const float*)d_in[7];
    const float* att_dst2 = (const float*)d_in[8];
    const float* b2 = (const float*)d_in[9];

    int N = in_sizes[0] / IN_CH;
    int E = in_sizes[1] / 2;

    char* wsp = (char*)d_ws;
    size_t off = 0;
    auto carve = [&](size_t bytes) -> void* {
        void* p = wsp + off;
        off = (off + bytes + 255) & ~(size_t)255;
        return p;
    };
    int nblocks = (E + RB - 1) / RB;
    int L = 256 * nblocks;

    uint32* packed = (uint32*)carve((size_t)E * 4);
    uint32* tmp = (uint32*)carve((size_t)E * 4);
    int* ghist = (int*)carve((size_t)L * 4);
    int* totals = (int*)carve(1024);
    int* gbase = (int*)carve(1032);
    int* offsets = (int*)carve((size_t)(N + 1) * 4);
    uint32* h1b = (uint32*)carve((size_t)N * C1 * 2);
    uint32* h2b = (uint32*)carve((size_t)N * OUT_CH * 2);
    uint32* out1h = (uint32*)carve((size_t)N * C1 * 2);
    float* as1 = (float*)carve((size_t)N * HEADS * 4);
    float* ad1 = (float*)carve((size_t)N * HEADS * 4);
    float* as2 = (float*)carve((size_t)N * 4);
    float* ad2 = (float*)carve((size_t)N * 4);

    // ---- CSR build: MSD-byte scatter + per-bucket LDS counting sort (5 kernels)
    pack_hist_kernel<<<nblocks, 256, 0, stream>>>(ei, E, packed, ghist, nblocks);
    rowscan_kernel<<<256, 256, 0, stream>>>(ghist, totals, nblocks);
    bases_kernel<<<1, 256, 0, stream>>>(totals, gbase, E);
    scatter_msd_kernel<<<nblocks, 256, 0, stream>>>(packed, tmp, ghist, gbase, E, nblocks);
    local_sort_kernel<<<(N + 255) / 256, 256, 0, stream>>>(tmp, packed, gbase, offsets, N, E);

    int nwaveblocks = (N * 64 + 255) / 256;
    int ngemmblocks = (N + 63) / 64;

    // layer 1
    gemm_dots_kernel<128, 128, 4, false>
        <<<ngemmblocks, 256, 0, stream>>>(x, W1, att_src1, att_dst1, h1b, as1, ad1, N);
    aggregate_kernel<128, 4, true, true>
        <<<nwaveblocks, 256, 0, stream>>>(h1b, as1, ad1, offsets, packed, b1, (void*)out1h, N);

    // layer 2
    gemm_dots_kernel<128, 64, 1, true><<<ngemmblocks, 256, 0, stream>>>(
        (const float*)out1h, W2, att_src2, att_dst2, h2b, as2, ad2, N);
    aggregate_kernel<64, 1, false, false>
        <<<nwaveblocks, 256, 0, stream>>>(h2b, as2, ad2, offsets, packed, b2, d_out, N);
}

// Round 13
// 126.349 us; speedup vs baseline: 1.2143x; 1.0025x over previous
//
#include <hip/hip_runtime.h>

#define NEG_SLOPE 0.2f

typedef unsigned int uint32;
typedef unsigned short ushort;
typedef unsigned long long u64;
typedef __fp16 f16x2 __attribute__((ext_vector_type(2)));
typedef __fp16 half8 __attribute__((ext_vector_type(8)));
typedef float f32x4 __attribute__((ext_vector_type(4)));

constexpr int IN_CH = 128;
constexpr int HID = 32;
constexpr int HEADS = 4;
constexpr int OUT_CH = 64;
constexpr int C1 = HEADS * HID; // 128
constexpr int RB = 1024;        // elements per radix block

__device__ inline uint32 pk_f16(float lo, float hi) {
    f16x2 h = __builtin_amdgcn_cvt_pkrtz(lo, hi);
    uint32 r;
    __builtin_memcpy(&r, &h, 4);
    return r;
}
__device__ inline float f16_lo(uint32 v) {
    f16x2 h;
    __builtin_memcpy(&h, &v, 4);
    return (float)h[0];
}
__device__ inline float f16_hi(uint32 v) {
    f16x2 h;
    __builtin_memcpy(&h, &v, 4);
    return (float)h[1];
}
__device__ inline float leaky(float e) {
    return fmaxf(e, 0.f) + NEG_SLOPE * fminf(e, 0.f);
}

// ========== CSR via MSD-byte scatter (digit = dst>>8) + per-bucket LDS counting sort ==========
// within-dst edge order is arbitrary (only permutes fp summation; tolerance covers it)
// per-(bucket,block) hist columns + scan keep the scatter contention-free (round-10 lesson:
// shared-cursor atomics on 256 counters cost +24 us). bases scan (totals -> gbase) is
// recomputed in each consumer's prologue (cheaper than a dedicated 1-block launch).

__global__ __launch_bounds__(256) void pack_hist_kernel(const int* __restrict__ ei, int E,
                                                        uint32* __restrict__ packed,
                                                        int* __restrict__ ghist, int nblocks) {
    __shared__ int lh[256];
    int t = threadIdx.x;
    lh[t] = 0;
    __syncthreads();
    int base0 = blockIdx.x * RB;
#pragma unroll
    for (int j = 0; j < 4; j++) {
        int e = base0 + j * 256 + t;
        if (e < E) {
            uint32 s = (uint32)ei[e], d = (uint32)ei[E + e];
            uint32 v = (d << 16) | s;
            packed[e] = v;
            atomicAdd(&lh[v >> 24], 1);
        }
    }
    __syncthreads();
    ghist[(size_t)t * nblocks + blockIdx.x] = lh[t];
}

// one block per bucket: exclusive scan of ghist row (along blocks), emit bucket total
__global__ __launch_bounds__(256) void rowscan_kernel(int* __restrict__ ghist,
                                                      int* __restrict__ totals, int nblocks) {
    __shared__ int ts[256];
    int b = blockIdx.x, t = threadIdx.x;
    int per = (nblocks + 255) >> 8;
    int* row = ghist + (size_t)b * nblocks;
    int v[8];
    int s = 0;
#pragma unroll
    for (int i = 0; i < 8; i++) {
        int idx = t * per + i;
        v[i] = (i < per && idx < nblocks) ? row[idx] : 0;
        s += v[i];
    }
    ts[t] = s;
    __syncthreads();
    for (int d = 1; d < 256; d <<= 1) {
        int x = (t >= d) ? ts[t - d] : 0;
        __syncthreads();
        ts[t] += x;
        __syncthreads();
    }
    int ex = (t > 0) ? ts[t - 1] : 0;
    if (t == 255) totals[b] = ts[255];
#pragma unroll
    for (int i = 0; i < 8; i++) {
        int idx = t * per + i;
        if (i < per && idx < nblocks) row[idx] = ex;
        ex += v[i];
    }
}

// in-LDS exclusive scan of totals[256] -> excl value for this thread's bucket
__device__ inline int scan_totals(const int* __restrict__ totals, int* cum, int t) {
    int v = totals[t];
    cum[t] = v;
    __syncthreads();
    for (int d = 1; d < 256; d <<= 1) {
        int x = (t >= d) ? cum[t - d] : 0;
        __syncthreads();
        cum[t] += x;
        __syncthreads();
    }
    return cum[t] - v;
}

__global__ __launch_bounds__(256) void scatter_msd_kernel(const uint32* __restrict__ in,
                                                          uint32* __restrict__ out,
                                                          const int* __restrict__ ghist,
                                                          const int* __restrict__ totals, int E,
                                                          int nblocks) {
    __shared__ int cum[256];
    __shared__ int lbase[256];
    int t = threadIdx.x;
    int gb = scan_totals(totals, cum, t);
    lbase[t] = ghist[(size_t)t * nblocks + blockIdx.x] + gb;
    __syncthreads();
    int base0 = blockIdx.x * RB;
#pragma unroll
    for (int j = 0; j < 4; j++) {
        int e = base0 + j * 256 + t;
        if (e < E) {
            uint32 v = in[e];
            int slot = atomicAdd(&lbase[v >> 24], 1);
            out[slot] = v;
        }
    }
}

// one block per 256-dst bucket: counting sort by (dst & 0xff) + emit offsets[]
__global__ __launch_bounds__(256) void local_sort_kernel(const uint32* __restrict__ in,
                                                         uint32* __restrict__ out,
                                                         const int* __restrict__ totals,
                                                         int* __restrict__ offsets, int N, int E) {
    __shared__ int scum[256];
    __shared__ int hist[256];
    __shared__ int cum[256];
    __shared__ int bounds[2];
    int b = blockIdx.x;
    int t = threadIdx.x;
    int gb = scan_totals(totals, scum, t);
    if (t == b) bounds[0] = gb;
    if (t == b + 1 || (b == 255 && t == 255)) bounds[1] = (b == 255) ? E : gb;
    hist[t] = 0;
    __syncthreads();
    int segstart = bounds[0];
    int segend = (b == 255) ? E : bounds[1];
    for (int i = segstart + t; i < segend; i += 256) atomicAdd(&hist[(in[i] >> 16) & 0xff], 1);
    __syncthreads();
    int v = hist[t];
    cum[t] = v;
    __syncthreads();
    for (int d = 1; d < 256; d <<= 1) {
        int x = (t >= d) ? cum[t - d] : 0;
        __syncthreads();
        cum[t] += x;
        __syncthreads();
    }
    int myExcl = cum[t] - v;
    int dstv = b * 256 + t;
    if (dstv < N) offsets[dstv] = segstart + myExcl;
    if (b == 0 && t == 0) offsets[N] = E;
    hist[t] = myExcl;
    __syncthreads();
    for (int i = segstart + t; i < segend; i += 256) {
        uint32 w = in[i];
        int slot = atomicAdd(&hist[(w >> 16) & 0xff], 1);
        out[segstart + slot] = w;
    }
}

// ---------------- MFMA f16 GEMM + attention dots + f16 pack ----------------
// BM=64 rows/block, whole K=128 staged once. 4 waves, wave w -> rows w*16..+15.
// A frag: lane l holds A[l&15][(l>>4)*8+j]; B frag: B[(l>>4)*8+j][l&15] via wt[col][k].
// D: col=lane&15, row=(lane>>4)*4+reg (m89-verified mapping).

template <int K, int COLS, int H, bool AF16>
__global__ __launch_bounds__(256) void gemm_dots_kernel(
    const float* __restrict__ A, const float* __restrict__ W,
    const float* __restrict__ att_s, const float* __restrict__ att_d,
    uint32* __restrict__ hb, float* __restrict__ as_, float* __restrict__ ad_, int N) {
    static_assert(K == 128, "");
    constexpr int CF = COLS / 16;
    __shared__ ushort xs[64][136];
    __shared__ ushort wt[COLS][136];
    int tid = threadIdx.x;
    int row0 = blockIdx.x * 64;

#pragma unroll
    for (int l = 0; l < 4; l++) {
        int idx = tid + l * 256;
        int row = idx >> 4, kc = idx & 15;
        uint4 pkv = make_uint4(0, 0, 0, 0);
        if (row0 + row < N) {
            if constexpr (AF16) {
                pkv = *(const uint4*)((const uint32*)A + (size_t)(row0 + row) * (K / 2) + kc * 4);
            } else {
                const float* ap = A + (size_t)(row0 + row) * K + kc * 8;
                float4 v0 = *(const float4*)ap;
                float4 v1 = *(const float4*)(ap + 4);
                pkv = make_uint4(pk_f16(v0.x, v0.y), pk_f16(v0.z, v0.w), pk_f16(v1.x, v1.y),
                                 pk_f16(v1.z, v1.w));
            }
        }
        *(uint4*)&xs[row][kc * 8] = pkv;
    }
    constexpr int NP = (K / 2) * COLS / 256;
#pragma unroll
    for (int l = 0; l < NP; l++) {
        int p = tid + l * 256;
        int col = p % COLS, kp = p / COLS;
        float v0 = W[(size_t)(2 * kp) * COLS + col];
        float v1 = W[(size_t)(2 * kp + 1) * COLS + col];
        *(uint32*)&wt[col][kp * 2] = pk_f16(v0, v1);
    }
    __syncthreads();

    int w = tid >> 6, l = tid & 63;
    int q = l & 15, g = l >> 4;

    half8 af[4];
#pragma unroll
    for (int ks = 0; ks < 4; ks++) af[ks] = *(const half8*)&xs[w * 16 + q][ks * 32 + g * 8];

    f32x4 accs[CF];
#pragma unroll
    for (int cf = 0; cf < CF; cf++) {
        f32x4 a = {0.f, 0.f, 0.f, 0.f};
#pragma unroll
        for (int ks = 0; ks < 4; ks++) {
            half8 bf = *(const half8*)&wt[cf * 16 + q][ks * 32 + g * 8];
            a = __builtin_amdgcn_mfma_f32_16x16x32_f16(af[ks], bf, a, 0, 0, 0);
        }
        accs[cf] = a;
    }

    float asf[CF], adf[CF];
#pragma unroll
    for (int cf = 0; cf < CF; cf++) {
        asf[cf] = att_s[cf * 16 + q];
        adf[cf] = att_d[cf * 16 + q];
    }

#pragma unroll
    for (int r = 0; r < 4; r++) {
        int n_r = row0 + w * 16 + g * 4 + r;
        uint32 dw[CF];
        float p0 = 0.f, p1 = 0.f, p2 = 0.f, p3 = 0.f;
        float d0 = 0.f, d1 = 0.f, d2 = 0.f, d3 = 0.f;
#pragma unroll
        for (int cf = 0; cf < CF; cf++) {
            float v = accs[cf][r];
            float nb = __shfl_xor(v, 1);
            float ev = (q & 1) ? nb : v;
            float ov = (q & 1) ? v : nb;
            dw[cf] = pk_f16(ev, ov);
            float cs = v * asf[cf], cd = v * adf[cf];
            if constexpr (H == 4) {
                if (cf < 2) {
                    p0 += cs;
                    d0 += cd;
                } else if (cf < 4) {
                    p1 += cs;
                    d1 += cd;
                } else if (cf < 6) {
                    p2 += cs;
                    d2 += cd;
                } else {
                    p3 += cs;
                    d3 += cd;
                }
            } else {
                p0 += cs;
                d0 += cd;
            }
        }
#pragma unroll
        for (int dd = 1; dd < 16; dd <<= 1) {
            p0 += __shfl_xor(p0, dd);
            d0 += __shfl_xor(d0, dd);
            if constexpr (H == 4) {
                p1 += __shfl_xor(p1, dd);
                d1 += __shfl_xor(d1, dd);
                p2 += __shfl_xor(p2, dd);
                d2 += __shfl_xor(d2, dd);
                p3 += __shfl_xor(p3, dd);
                d3 += __shfl_xor(d3, dd);
            }
        }
        if (n_r < N) {
            if ((q & 1) == 0) {
                uint32* hp = hb + (size_t)n_r * (COLS / 2) + (q >> 1);
#pragma unroll
                for (int cf = 0; cf < CF; cf++) hp[cf * 8] = dw[cf];
            }
            if constexpr (H == 4) {
                if ((q >> 2) == r) {
                    int hh = q & 3;
                    float vs = hh == 0 ? p0 : hh == 1 ? p1 : hh == 2 ? p2 : p3;
                    float vd = hh == 0 ? d0 : hh == 1 ? d1 : hh == 2 ? d2 : d3;
                    as_[(size_t)n_r * 4 + hh] = vs;
                    ad_[(size_t)n_r * 4 + hh] = vd;
                }
            } else {
                if (q == r) {
                    as_[n_r] = p0;
                    ad_[n_r] = d0;
                }
            }
        }
    }
}

// ---------------- fused single-pass segment softmax + aggregation ----------------
// XCD-bijective block swizzle (m204): consecutive dst ranges stay on one XCD so
// csr/offsets cachelines are fetched by a single XCD's L2.

template <int C, int H, bool RELU, bool OUTF16>
__global__ __launch_bounds__(256) void aggregate_kernel(
    const uint32* __restrict__ hb, const float* __restrict__ as_,
    const float* __restrict__ ad_, const int* __restrict__ offsets,
    const uint32* __restrict__ csr, const float* __restrict__ bias, void* __restrict__ outp,
    int N) {
    __shared__ float plds[4][64 * H];
    __shared__ int slds[4][64];
    int bid = blockIdx.x;
    int nwg = gridDim.x;
    int qq = nwg >> 3, rr = nwg & 7;
    int xcd = bid & 7, jj = bid >> 3;
    int work = (xcd < rr ? xcd * (qq + 1) : rr * (qq + 1) + (xcd - rr) * qq) + jj;
    int lane = threadIdx.x & 63;
    int wslot = threadIdx.x >> 6;
    int n = work * 4 + wslot;
    if (n >= N) return;
    int off = offsets[n];
    int deg = offsets[n + 1] - off;

    float ad[H], s[H];
#pragma unroll
    for (int h = 0; h < H; h++) {
        ad[h] = ad_[(size_t)n * H + h];
        s[h] = 0.f;
    }

    constexpr int G = C / 8;
    constexpr int EPI = 64 / G;
    int eg = lane / G;
    int cl = lane % G;
    int hsel = (H == 4) ? (cl >> 2) : 0;
    float acc[8];
#pragma unroll
    for (int j = 0; j < 8; j++) acc[j] = 0.f;

    for (int base = 0; base <= deg; base += 64) {
        int my = base + lane;
        int cnt = min(64, deg + 1 - base);
        if (my <= deg) {
            int si = (my < deg) ? (int)(csr[off + my] & 0xffffu) : n;
            slds[wslot][lane] = si;
            if constexpr (H == 4) {
                float4 a = ((const float4*)as_)[si];
                float q0 = __expf(fminf(leaky(a.x + ad[0]), 80.f));
                float q1 = __expf(fminf(leaky(a.y + ad[1]), 80.f));
                float q2 = __expf(fminf(leaky(a.z + ad[2]), 80.f));
                float q3 = __expf(fminf(leaky(a.w + ad[3]), 80.f));
                s[0] += q0;
                s[1] += q1;
                s[2] += q2;
                s[3] += q3;
                ((float4*)plds[wslot])[lane] = make_float4(q0, q1, q2, q3);
            } else {
                float p = __expf(fminf(leaky(as_[si] + ad[0]), 80.f));
                s[0] += p;
                plds[wslot][lane] = p;
            }
        }
        int t2 = 0;
        for (; t2 + 2 * EPI <= cnt; t2 += 2 * EPI) {
            int tA = t2 + eg, tB = t2 + EPI + eg;
            int srcA = slds[wslot][tA];
            int srcB = slds[wslot][tB];
            float alA = plds[wslot][tA * H + hsel];
            float alB = plds[wslot][tB * H + hsel];
            uint4 uA = *(const uint4*)(hb + (size_t)srcA * (C / 2) + cl * 4);
            uint4 uB = *(const uint4*)(hb + (size_t)srcB * (C / 2) + cl * 4);
            acc[0] = fmaf(alA, f16_lo(uA.x), acc[0]);
            acc[1] = fmaf(alA, f16_hi(uA.x), acc[1]);
            acc[2] = fmaf(alA, f16_lo(uA.y), acc[2]);
            acc[3] = fmaf(alA, f16_hi(uA.y), acc[3]);
            acc[4] = fmaf(alA, f16_lo(uA.z), acc[4]);
            acc[5] = fmaf(alA, f16_hi(uA.z), acc[5]);
            acc[6] = fmaf(alA, f16_lo(uA.w), acc[6]);
            acc[7] = fmaf(alA, f16_hi(uA.w), acc[7]);
            acc[0] = fmaf(alB, f16_lo(uB.x), acc[0]);
            acc[1] = fmaf(alB, f16_hi(uB.x), acc[1]);
            acc[2] = fmaf(alB, f16_lo(uB.y), acc[2]);
            acc[3] = fmaf(alB, f16_hi(uB.y), acc[3]);
            acc[4] = fmaf(alB, f16_lo(uB.z), acc[4]);
            acc[5] = fmaf(alB, f16_hi(uB.z), acc[5]);
            acc[6] = fmaf(alB, f16_lo(uB.w), acc[6]);
            acc[7] = fmaf(alB, f16_hi(uB.w), acc[7]);
        }
        for (; t2 < cnt; t2 += EPI) {
            int te = t2 + eg;
            bool valid = te < cnt;
            int tc = valid ? te : 0;
            int src = slds[wslot][tc];
            float al = plds[wslot][tc * H + hsel];
            al = valid ? al : 0.f;
            uint4 u = *(const uint4*)(hb + (size_t)src * (C / 2) + cl * 4);
            acc[0] = fmaf(al, f16_lo(u.x), acc[0]);
            acc[1] = fmaf(al, f16_hi(u.x), acc[1]);
            acc[2] = fmaf(al, f16_lo(u.y), acc[2]);
            acc[3] = fmaf(al, f16_hi(u.y), acc[3]);
            acc[4] = fmaf(al, f16_lo(u.z), acc[4]);
            acc[5] = fmaf(al, f16_hi(u.z), acc[5]);
            acc[6] = fmaf(al, f16_lo(u.w), acc[6]);
            acc[7] = fmaf(al, f16_hi(u.w), acc[7]);
        }
    }

#pragma unroll
    for (int d = 1; d < 64; d <<= 1)
#pragma unroll
        for (int h = 0; h < H; h++) s[h] += __shfl_xor(s[h], d);
#pragma unroll
    for (int d = G; d < 64; d <<= 1)
#pragma unroll
        for (int j = 0; j < 8; j++) acc[j] += __shfl_xor(acc[j], d);

    if (eg == 0) {
        float inv = 1.f / s[hsel];
        int c = cl * 8;
        float o[8];
#pragma unroll
        for (int j = 0; j < 8; j++) {
            o[j] = fmaf(acc[j], inv, bias[c + j]);
            if (RELU) o[j] = fmaxf(o[j], 0.f);
        }
        if constexpr (OUTF16) {
            uint4 pkv = make_uint4(pk_f16(o[0], o[1]), pk_f16(o[2], o[3]), pk_f16(o[4], o[5]),
                                   pk_f16(o[6], o[7]));
            *(uint4*)((uint32*)outp + (size_t)n * (C / 2) + cl * 4) = pkv;
        } else {
            float* out = (float*)outp;
            *(float4*)(out + (size_t)n * C + c) = make_float4(o[0], o[1], o[2], o[3]);
            *(float4*)(out + (size_t)n * C + c + 4) = make_float4(o[4], o[5], o[6], o[7]);
        }
    }
}

// ---------------- launch ----------------

extern "C" void kernel_launch(void* const* d_in, const int* in_sizes, int n_in,
                              void* d_out, int out_size, void* d_ws, size_t ws_size,
                              hipStream_t stream) {
    const float* x = (const float*)d_in[0];
    const int* ei = (const int*)d_in[1];
    const float* W1 = (const float*)d_in[2];
    const float* att_src1 = (const float*)d_in[3];
    const float* att_dst1 = (const float*)d_in[4];
    const float* b1 = (const float*)d_in[5];
    const float* W2 = (const float*)d_in[6];
    const float* att_src2 = (const float*)d_in[7];
    const float* att_dst2 = (const float*)d_in[8];
    const float* b2 = (const float*)d_in[9];

    int N = in_sizes[0] / IN_CH;
    int E = in_sizes[1] / 2;

    char* wsp = (char*)d_ws;
    size_t off = 0;
    auto carve = [&](size_t bytes) -> void* {
        void* p = wsp + off;
        off = (off + bytes + 255) & ~(size_t)255;
        return p;
    };
    int nblocks = (E + RB - 1) / RB;
    int L = 256 * nblocks;

    uint32* packed = (uint32*)carve((size_t)E * 4);
    uint32* tmp = (uint32*)carve((size_t)E * 4);
    int* ghist = (int*)carve((size_t)L * 4);
    int* totals = (int*)carve(1024);
    int* offsets = (int*)carve((size_t)(N + 1) * 4);
    uint32* h1b = (uint32*)carve((size_t)N * C1 * 2);
    uint32* h2b = (uint32*)carve((size_t)N * OUT_CH * 2);
    uint32* out1h = (uint32*)carve((size_t)N * C1 * 2);
    float* as1 = (float*)carve((size_t)N * HEADS * 4);
    float* ad1 = (float*)carve((size_t)N * HEADS * 4);
    float* as2 = (float*)carve((size_t)N * 4);
    float* ad2 = (float*)carve((size_t)N * 4);

    // ---- CSR build: MSD-byte scatter + per-bucket LDS counting sort (4 kernels)
    pack_hist_kernel<<<nblocks, 256, 0, stream>>>(ei, E, packed, ghist, nblocks);
    rowscan_kernel<<<256, 256, 0, stream>>>(ghist, totals, nblocks);
    scatter_msd_kernel<<<nblocks, 256, 0, stream>>>(packed, tmp, ghist, totals, E, nblocks);
    local_sort_kernel<<<(N + 255) / 256, 256, 0, stream>>>(tmp, packed, totals, offsets, N, E);

    int nwaveblocks = (N * 64 + 255) / 256;
    int ngemmblocks = (N + 63) / 64;

    // layer 1
    gemm_dots_kernel<128, 128, 4, false>
        <<<ngemmblocks, 256, 0, stream>>>(x, W1, att_src1, att_dst1, h1b, as1, ad1, N);
    aggregate_kernel<128, 4, true, true>
        <<<nwaveblocks, 256, 0, stream>>>(h1b, as1, ad1, offsets, packed, b1, (void*)out1h, N);

    // layer 2
    gemm_dots_kernel<128, 64, 1, true><<<ngemmblocks, 256, 0, stream>>>(
        (const float*)out1h, W2, att_src2, att_dst2, h2b, as2, ad2, N);
    aggregate_kernel<64, 1, false, false>
        <<<nwaveblocks, 256, 0, stream>>>(h2b, as2, ad2, offsets, packed, b2, d_out, N);
}